// Round 3
// baseline (742.675 us; speedup 1.0000x reference)
//
#include <hip/hip_runtime.h>
#include <math.h>

#define MAXK 64
#define HDIM 128
#define FDIM 64
#define KPAD 68   // 67 inputs + 1 pad to keep float4 rows
#define RB   16   // rows per MLP work-item chunk

// order-preserving float<->uint mapping for exact fp32 atomicMax
__device__ __forceinline__ unsigned fkey(float f) {
    unsigned b = __float_as_uint(f);
    return (b & 0x80000000u) ? ~b : (b | 0x80000000u);
}
__device__ __forceinline__ float funkey(unsigned k) {
    unsigned b = (k & 0x80000000u) ? (k & 0x7FFFFFFFu) : ~k;
    return __uint_as_float(b);
}

// ---------------------------------------------------------------------------
// Kernel 1: ball query. One 256-thread block per query; 1024 candidates per
// iteration (4 ballot chunks per wave), ordered compaction across the 16
// chunks via a double-buffered LDS mask exchange -> ONE barrier per 1024
// candidates. Binary search done redundantly by every thread (SIMT-free).
// ---------------------------------------------------------------------------
__global__ __launch_bounds__(256) void nbr_kernel(
    const float* __restrict__ pos, const int* __restrict__ batch,
    const int* __restrict__ key_idx, int N, int M,
    int* __restrict__ nbr, int* __restrict__ cnt_out)
{
    __shared__ unsigned long long smask[2][16];

    int m = blockIdx.x;
    int tid = threadIdx.x, lane = tid & 63, w = tid >> 6;

    int qi = key_idx[m];
    int qb = batch[qi];
    float qx = pos[3*qi+0], qy = pos[3*qi+1], qz = pos[3*qi+2];

    int lo, hi;
    { int a=0, b=N; while (a<b){ int mid=(a+b)>>1; if (batch[mid] <  qb) a=mid+1; else b=mid; } lo=a; }
    { int a=lo, b=N; while (a<b){ int mid=(a+b)>>1; if (batch[mid] <= qb) a=mid+1; else b=mid; } hi=a; }

    // NOTE: (float)0.04 != 0.2f*0.2f (1 ulp). Match reference d2 formula
    // exactly, no fma contraction (round-2 absmax 3e-5 => classification
    // bit-exact; do not perturb).
    const float R2 = 0.04f;
    float q2 = __fadd_rn(__fadd_rn(__fmul_rn(qx,qx), __fmul_rn(qy,qy)), __fmul_rn(qz,qz));

    int cnt = 0, buf = 0;
    for (int base = lo; base < hi && cnt < MAXK; base += 1024) {
        bool v4[4]; unsigned long long m4[4]; int j4[4];
        #pragma unroll
        for (int sub = 0; sub < 4; ++sub) {
            int j = base + (w*4 + sub)*64 + lane;
            bool v = false;
            if (j < hi) {
                float px = pos[3*j+0], py = pos[3*j+1], pz = pos[3*j+2];
                float p2 = __fadd_rn(__fadd_rn(__fmul_rn(px,px), __fmul_rn(py,py)), __fmul_rn(pz,pz));
                float dt = __fadd_rn(__fadd_rn(__fmul_rn(qx,px), __fmul_rn(qy,py)), __fmul_rn(qz,pz));
                float d2 = __fsub_rn(__fadd_rn(q2, p2), __fmul_rn(2.0f, dt));
                v = (d2 <= R2);
            }
            m4[sub] = __ballot(v); v4[sub] = v; j4[sub] = j;
            if (lane == 0) smask[buf][w*4 + sub] = m4[sub];
        }
        __syncthreads();
        int run = cnt, pres[4];
        #pragma unroll
        for (int t = 0; t < 16; ++t) {
            if ((t >> 2) == w) pres[t & 3] = run;
            run += (int)__popcll(smask[buf][t]);
        }
        #pragma unroll
        for (int sub = 0; sub < 4; ++sub) {
            if (v4[sub]) {
                int slot = pres[sub] + (int)__popcll(m4[sub] & ((1ull << lane) - 1ull));
                if (slot < MAXK) nbr[m*MAXK + slot] = j4[sub];
            }
        }
        cnt = run;
        buf ^= 1;   // double buffer: safe with one barrier per iteration
    }
    if (cnt > MAXK) cnt = MAXK;
    if (tid == 0) cnt_out[m] = cnt;
}

// ---------------------------------------------------------------------------
// Kernel 2: MLP partial. One 128-thread block per (query, 16-row chunk) ->
// uniform work items, no imbalance. Thread owns one output channel.
// W1 column in regs; W2 column in 4x32 register chunks (VGPR diet -> 4
// waves/SIMD). Partial per-channel max combined via exact uint atomicMax.
// ---------------------------------------------------------------------------
__global__ __launch_bounds__(128, 4) void mlp_kernel(
    const float* __restrict__ x, const float* __restrict__ pos,
    const float* __restrict__ W1, const float* __restrict__ b1,
    const float* __restrict__ W2, const float* __restrict__ b2,
    const int* __restrict__ key_idx,
    const int* __restrict__ nbr, const int* __restrict__ cnt_in,
    unsigned* __restrict__ keys, int M)
{
    __shared__ __align__(16) float A[RB][KPAD];    // 4.35 KB
    __shared__ __align__(16) float Hs[RB][HDIM];   // 8 KB
    __shared__ int nidx[RB];

    int bm = blockIdx.x;
    int m  = bm >> 2, ch = bm & 3;
    int cnt = cnt_in[m];
    int rowbase = ch * RB;
    if (rowbase >= cnt) return;          // uniform across block
    int rv = min(cnt - rowbase, RB);

    int tid = threadIdx.x;               // channel c = tid
    int qi  = key_idx[m];
    float qx = pos[3*qi+0], qy = pos[3*qi+1], qz = pos[3*qi+2];

    if (tid < rv) nidx[tid] = nbr[m*MAXK + rowbase + tid];
    __syncthreads();

    // stage A = [x_j | pos_j - q | 0]: 8 threads per row, 2 float4 each
    {
        int r = tid >> 3, part = tid & 7;
        if (r < rv) {
            int idx = nidx[r];
            const float4* src = reinterpret_cast<const float4*>(x + (size_t)idx*FDIM + part*8);
            float4* dst = reinterpret_cast<float4*>(&A[r][part*8]);
            dst[0] = src[0]; dst[1] = src[1];
        }
        if (tid < rv) {
            int idx = nidx[tid];
            A[tid][64] = pos[3*idx+0] - qx;
            A[tid][65] = pos[3*idx+1] - qy;
            A[tid][66] = pos[3*idx+2] - qz;
            A[tid][67] = 0.f;
        }
    }

    float w1c[KPAD];
    #pragma unroll
    for (int k = 0; k < 67; ++k) w1c[k] = W1[k*HDIM + tid];
    w1c[67] = 0.f;
    float b1c = b1[tid];
    __syncthreads();

    // ---- layer 1: 4 rows in flight; garbage rows (>= rv) never stored ----
    #pragma unroll
    for (int o = 0; o < 4; ++o) {
        int ra = o*4;
        if (ra >= rv) break;
        const float4* A0 = reinterpret_cast<const float4*>(&A[ra+0][0]);
        const float4* A1 = reinterpret_cast<const float4*>(&A[ra+1 < RB ? ra+1 : ra][0]);
        const float4* A2 = reinterpret_cast<const float4*>(&A[ra+2 < RB ? ra+2 : ra][0]);
        const float4* A3 = reinterpret_cast<const float4*>(&A[ra+3 < RB ? ra+3 : ra][0]);
        float a0 = b1c, a1 = b1c, a2 = b1c, a3 = b1c;
        #pragma unroll
        for (int kk = 0; kk < 17; ++kk) {
            float4 v0 = A0[kk], v1 = A1[kk], v2 = A2[kk], v3 = A3[kk];
            float u0 = w1c[4*kk+0], u1 = w1c[4*kk+1], u2 = w1c[4*kk+2], u3 = w1c[4*kk+3];
            a0 = fmaf(v0.x,u0,a0); a1 = fmaf(v1.x,u0,a1); a2 = fmaf(v2.x,u0,a2); a3 = fmaf(v3.x,u0,a3);
            a0 = fmaf(v0.y,u1,a0); a1 = fmaf(v1.y,u1,a1); a2 = fmaf(v2.y,u1,a2); a3 = fmaf(v3.y,u1,a3);
            a0 = fmaf(v0.z,u2,a0); a1 = fmaf(v1.z,u2,a1); a2 = fmaf(v2.z,u2,a2); a3 = fmaf(v3.z,u2,a3);
            a0 = fmaf(v0.w,u3,a0); a1 = fmaf(v1.w,u3,a1); a2 = fmaf(v2.w,u3,a2); a3 = fmaf(v3.w,u3,a3);
        }
        Hs[ra+0][tid] = fmaxf(a0, 0.f);
        if (ra+1 < rv) Hs[ra+1][tid] = fmaxf(a1, 0.f);
        if (ra+2 < rv) Hs[ra+2][tid] = fmaxf(a2, 0.f);
        if (ra+3 < rv) Hs[ra+3][tid] = fmaxf(a3, 0.f);
    }
    __syncthreads();

    // ---- layer 2: W2 in 4 chunks of 32 regs; 16 independent accumulators.
    // Rows >= rv may read uninit LDS (possibly NaN) -> acc discarded below.
    float acc[RB];
    float b2c = b2[tid];
    #pragma unroll
    for (int r = 0; r < RB; ++r) acc[r] = b2c;
    #pragma unroll
    for (int cc = 0; cc < 4; ++cc) {
        float w2c[32];
        #pragma unroll
        for (int k = 0; k < 32; ++k) w2c[k] = W2[(cc*32 + k)*HDIM + tid];
        #pragma unroll
        for (int kk = 0; kk < 8; ++kk) {
            float u0 = w2c[kk*4+0], u1 = w2c[kk*4+1], u2 = w2c[kk*4+2], u3 = w2c[kk*4+3];
            #pragma unroll
            for (int r = 0; r < RB; ++r) {
                float4 h = *reinterpret_cast<const float4*>(&Hs[r][cc*32 + kk*4]);
                acc[r] = fmaf(h.x, u0, acc[r]);
                acc[r] = fmaf(h.y, u1, acc[r]);
                acc[r] = fmaf(h.z, u2, acc[r]);
                acc[r] = fmaf(h.w, u3, acc[r]);
            }
        }
    }
    float mx = -INFINITY;
    #pragma unroll
    for (int r = 0; r < RB; ++r) if (r < rv) mx = fmaxf(mx, acc[r]);
    atomicMax(&keys[(size_t)m*HDIM + tid], fkey(mx));
}

// ---------------------------------------------------------------------------
// Kernel 3: unmap keys, L2 normalize, store. One wave per query.
// ---------------------------------------------------------------------------
__global__ __launch_bounds__(64) void norm_kernel(
    const unsigned* __restrict__ keys, float* __restrict__ out, int M)
{
    int m = blockIdx.x, lane = threadIdx.x;
    unsigned k0 = keys[(size_t)m*HDIM + lane];
    unsigned k1 = keys[(size_t)m*HDIM + 64 + lane];
    float v0 = (k0 == 0u) ? 0.f : funkey(k0);   // key 0 <=> no neighbors
    float v1 = (k1 == 0u) ? 0.f : funkey(k1);
    float s = v0*v0 + v1*v1;
    #pragma unroll
    for (int o = 32; o > 0; o >>= 1) s += __shfl_xor(s, o, 64);
    float nrm = fmaxf(sqrtf(s), 1e-12f);
    out[(size_t)m*HDIM + lane]      = v0 / nrm;
    out[(size_t)m*HDIM + 64 + lane] = v1 / nrm;
}

extern "C" void kernel_launch(void* const* d_in, const int* in_sizes, int n_in,
                              void* d_out, int out_size, void* d_ws, size_t ws_size,
                              hipStream_t stream)
{
    const float* x       = (const float*)d_in[0];
    const float* pos     = (const float*)d_in[1];
    const float* W1      = (const float*)d_in[2];
    const float* b1      = (const float*)d_in[3];
    const float* W2      = (const float*)d_in[4];
    const float* b2      = (const float*)d_in[5];
    const int*   batch   = (const int*)d_in[6];
    const int*   key_idx = (const int*)d_in[7];

    int N = in_sizes[6];   // 100000
    int M = in_sizes[7];   // 2048

    int*      nbr  = (int*)d_ws;                       // [M*64]
    int*      cnt  = nbr + (size_t)M * MAXK;           // [M]
    unsigned* keys = (unsigned*)(cnt + M);             // [M*128]

    nbr_kernel<<<M, 256, 0, stream>>>(pos, batch, key_idx, N, M, nbr, cnt);
    hipMemsetAsync(keys, 0, (size_t)M * HDIM * sizeof(unsigned), stream);
    mlp_kernel<<<M*4, 128, 0, stream>>>(x, pos, W1, b1, W2, b2, key_idx, nbr, cnt,
                                        keys, M);
    norm_kernel<<<M, 64, 0, stream>>>(keys, (float*)d_out, M);
}

// Round 4
// 470.106 us; speedup vs baseline: 1.5798x; 1.5798x over previous
//
#include <hip/hip_runtime.h>
#include <math.h>

#define MAXK 64
#define HDIM 128
#define FDIM 64
#define KPAD 68   // 67 inputs + 1 pad to keep float4 rows
#define RB   16   // rows per MLP chunk

// ---------------------------------------------------------------------------
// Fully fused: ball-query scan + PointNet MLP + max-aggregate + L2 normalize.
// One 256-thread block per query.
//
// Scan: 4 waves, each scans a contiguous quarter of the query's batch segment
// (batch[] is sorted) with 4-ballot ILP, wave-local ordered compaction into a
// private LDS list, NO barriers. A wave stops once it has 64 locals (only its
// first 64 can be in the global first-64). One barrier + ordered 4-list merge
// == PyG "first MAX_NBRS valid neighbors in index order" exactly.
//
// MLP: chunks of 16 rows. Layer1: thread owns channel c, W1 column in regs
// (the ONLY large register array - round-3 spill lesson), 4-row ILP.
// Layer2: 8 NAMED accumulators, W2 streamed from global (L1/L2-resident).
// A/Hs reads are wave-uniform LDS broadcasts (conflict-free).
// ---------------------------------------------------------------------------
__global__ __launch_bounds__(256) void desc_kernel(
    const float* __restrict__ x, const float* __restrict__ pos,
    const float* __restrict__ W1, const float* __restrict__ b1,
    const float* __restrict__ W2, const float* __restrict__ b2,
    const int* __restrict__ batch, const int* __restrict__ key_idx,
    float* __restrict__ out, int N, int M)
{
    __shared__ int lists[4][MAXK];
    __shared__ int lcnt[4];
    __shared__ int nidx[MAXK];
    __shared__ __align__(16) float A[RB][KPAD];    // 4.35 KB
    __shared__ __align__(16) float Hs[RB][HDIM];   // 8 KB
    __shared__ float pmax[2][HDIM];
    __shared__ float rsum[2];

    int m   = blockIdx.x;
    int tid = threadIdx.x, lane = tid & 63, w = tid >> 6;

    int qi = key_idx[m];
    int qb = batch[qi];
    float qx = pos[3*qi+0], qy = pos[3*qi+1], qz = pos[3*qi+2];

    // redundant per-thread binary search (L1-hot after first block per CU)
    int lo, hi;
    { int a=0, b=N; while (a<b){ int mid=(a+b)>>1; if (batch[mid] <  qb) a=mid+1; else b=mid; } lo=a; }
    { int a=lo, b=N; while (a<b){ int mid=(a+b)>>1; if (batch[mid] <= qb) a=mid+1; else b=mid; } hi=a; }

    // NOTE: (float)0.04 != 0.2f*0.2f (1 ulp). Match reference d2 formula
    // exactly, no fma contraction (rounds 1-3 absmax <= 2.4e-4; keep).
    const float R2 = 0.04f;
    float q2 = __fadd_rn(__fadd_rn(__fmul_rn(qx,qx), __fmul_rn(qy,qy)), __fmul_rn(qz,qz));

    // ---- phase 1: barrier-free per-wave quarter scan ----
    {
        int seg   = hi - lo;
        int qlen  = (seg + 3) >> 2;
        int start = lo + w*qlen;
        int qend  = min(start + qlen, hi);
        int lc = 0;
        for (int base = start; base < qend && lc < MAXK; base += 256) {
            unsigned long long mk[4]; bool vv[4]; int jj[4];
            #pragma unroll
            for (int sub = 0; sub < 4; ++sub) {
                int j = base + sub*64 + lane;
                bool v = false;
                if (j < qend) {
                    float px = pos[3*j+0], py = pos[3*j+1], pz = pos[3*j+2];
                    float p2 = __fadd_rn(__fadd_rn(__fmul_rn(px,px), __fmul_rn(py,py)), __fmul_rn(pz,pz));
                    float dt = __fadd_rn(__fadd_rn(__fmul_rn(qx,px), __fmul_rn(qy,py)), __fmul_rn(qz,pz));
                    float d2 = __fsub_rn(__fadd_rn(q2, p2), __fmul_rn(2.0f, dt));
                    v = (d2 <= R2);
                }
                mk[sub] = __ballot(v); vv[sub] = v; jj[sub] = j;
            }
            #pragma unroll
            for (int sub = 0; sub < 4; ++sub) {
                if (vv[sub]) {
                    int slot = lc + (int)__popcll(mk[sub] & ((1ull << lane) - 1ull));
                    if (slot < MAXK) lists[w][slot] = jj[sub];
                }
                lc += (int)__popcll(mk[sub]);
            }
        }
        if (lane == 0) lcnt[w] = min(lc, MAXK);
    }
    __syncthreads();

    // ---- ordered merge of the 4 quarter lists ----
    int c0 = lcnt[0], c1 = lcnt[1], c2 = lcnt[2], c3 = lcnt[3];
    int cnt = min(MAXK, c0 + c1 + c2 + c3);
    if (tid < cnt) {
        int k = tid, q, off;
        if      (k < c0)          { q = 0; off = k; }
        else if (k < c0+c1)       { q = 1; off = k - c0; }
        else if (k < c0+c1+c2)    { q = 2; off = k - c0 - c1; }
        else                      { q = 3; off = k - c0 - c1 - c2; }
        nidx[tid] = lists[q][off];
    }

    int c = tid & 127, g = tid >> 7;          // channel, row-parity group
    float w1c[KPAD];
    #pragma unroll
    for (int k = 0; k < 67; ++k) w1c[k] = W1[k*HDIM + c];
    w1c[67] = 0.f;
    float b1c = b1[c], b2c = b2[c];
    float mx = -INFINITY;
    __syncthreads();                          // nidx ready

    // ---- phase 2: MLP over chunks of 16 rows ----
    for (int ch = 0; ch*RB < cnt; ++ch) {
        int rv = min(cnt - ch*RB, RB);

        // stage A = [x_j | pos_j - q | 0]: 16 threads per row, 1 float4 each
        {
            int r = tid >> 4, p = tid & 15;
            if (r < rv) {
                int idx = nidx[ch*RB + r];
                *reinterpret_cast<float4*>(&A[r][p*4]) =
                    *reinterpret_cast<const float4*>(x + (size_t)idx*FDIM + p*4);
            }
            if (tid < rv) {
                int idx = nidx[ch*RB + tid];
                A[tid][64] = pos[3*idx+0] - qx;
                A[tid][65] = pos[3*idx+1] - qy;
                A[tid][66] = pos[3*idx+2] - qz;
                A[tid][67] = 0.f;
            }
        }
        __syncthreads();

        // layer 1: group g rows {g, g+2, ...}; 4-row ILP x 2 halves
        #pragma unroll
        for (int half = 0; half < 2; ++half) {
            int ra = g + half*8;
            if (ra < rv) {
                int r1 = (ra+2 < rv) ? ra+2 : ra;
                int r2 = (ra+4 < rv) ? ra+4 : ra;
                int r3 = (ra+6 < rv) ? ra+6 : ra;
                const float4* A0 = reinterpret_cast<const float4*>(&A[ra][0]);
                const float4* A1 = reinterpret_cast<const float4*>(&A[r1][0]);
                const float4* A2 = reinterpret_cast<const float4*>(&A[r2][0]);
                const float4* A3 = reinterpret_cast<const float4*>(&A[r3][0]);
                float a0 = b1c, a1 = b1c, a2 = b1c, a3 = b1c;
                #pragma unroll
                for (int kk = 0; kk < 17; ++kk) {
                    float4 v0 = A0[kk], v1 = A1[kk], v2 = A2[kk], v3 = A3[kk];
                    float u0 = w1c[4*kk+0], u1 = w1c[4*kk+1], u2 = w1c[4*kk+2], u3 = w1c[4*kk+3];
                    a0 = fmaf(v0.x,u0,a0); a1 = fmaf(v1.x,u0,a1); a2 = fmaf(v2.x,u0,a2); a3 = fmaf(v3.x,u0,a3);
                    a0 = fmaf(v0.y,u1,a0); a1 = fmaf(v1.y,u1,a1); a2 = fmaf(v2.y,u1,a2); a3 = fmaf(v3.y,u1,a3);
                    a0 = fmaf(v0.z,u2,a0); a1 = fmaf(v1.z,u2,a1); a2 = fmaf(v2.z,u2,a2); a3 = fmaf(v3.z,u2,a3);
                    a0 = fmaf(v0.w,u3,a0); a1 = fmaf(v1.w,u3,a1); a2 = fmaf(v2.w,u3,a2); a3 = fmaf(v3.w,u3,a3);
                }
                Hs[ra][c] = fmaxf(a0, 0.f);
                if (ra+2 < rv) Hs[ra+2][c] = fmaxf(a1, 0.f);
                if (ra+4 < rv) Hs[ra+4][c] = fmaxf(a2, 0.f);
                if (ra+6 < rv) Hs[ra+6][c] = fmaxf(a3, 0.f);
            }
        }
        __syncthreads();

        // layer 2: 8 named accumulators (rows g, g+2, ..., g+14), W2 streamed.
        // Invalid rows clamp to row 0 (always written when chunk exists).
        {
            const float4* h0 = reinterpret_cast<const float4*>(&Hs[(g    < rv) ? g    : 0][0]);
            const float4* h1 = reinterpret_cast<const float4*>(&Hs[(g+ 2 < rv) ? g+ 2 : 0][0]);
            const float4* h2 = reinterpret_cast<const float4*>(&Hs[(g+ 4 < rv) ? g+ 4 : 0][0]);
            const float4* h3 = reinterpret_cast<const float4*>(&Hs[(g+ 6 < rv) ? g+ 6 : 0][0]);
            const float4* h4 = reinterpret_cast<const float4*>(&Hs[(g+ 8 < rv) ? g+ 8 : 0][0]);
            const float4* h5 = reinterpret_cast<const float4*>(&Hs[(g+10 < rv) ? g+10 : 0][0]);
            const float4* h6 = reinterpret_cast<const float4*>(&Hs[(g+12 < rv) ? g+12 : 0][0]);
            const float4* h7 = reinterpret_cast<const float4*>(&Hs[(g+14 < rv) ? g+14 : 0][0]);
            float a0=b2c,a1=b2c,a2=b2c,a3=b2c,a4=b2c,a5=b2c,a6=b2c,a7=b2c;
            #pragma unroll 4
            for (int k4 = 0; k4 < HDIM; k4 += 4) {
                float u0 = W2[(k4+0)*HDIM + c];
                float u1 = W2[(k4+1)*HDIM + c];
                float u2 = W2[(k4+2)*HDIM + c];
                float u3 = W2[(k4+3)*HDIM + c];
                int ki = k4 >> 2;
                float4 v0 = h0[ki], v1 = h1[ki], v2 = h2[ki], v3 = h3[ki];
                float4 v4 = h4[ki], v5 = h5[ki], v6 = h6[ki], v7 = h7[ki];
                a0 = fmaf(v0.x,u0,a0); a0 = fmaf(v0.y,u1,a0); a0 = fmaf(v0.z,u2,a0); a0 = fmaf(v0.w,u3,a0);
                a1 = fmaf(v1.x,u0,a1); a1 = fmaf(v1.y,u1,a1); a1 = fmaf(v1.z,u2,a1); a1 = fmaf(v1.w,u3,a1);
                a2 = fmaf(v2.x,u0,a2); a2 = fmaf(v2.y,u1,a2); a2 = fmaf(v2.z,u2,a2); a2 = fmaf(v2.w,u3,a2);
                a3 = fmaf(v3.x,u0,a3); a3 = fmaf(v3.y,u1,a3); a3 = fmaf(v3.z,u2,a3); a3 = fmaf(v3.w,u3,a3);
                a4 = fmaf(v4.x,u0,a4); a4 = fmaf(v4.y,u1,a4); a4 = fmaf(v4.z,u2,a4); a4 = fmaf(v4.w,u3,a4);
                a5 = fmaf(v5.x,u0,a5); a5 = fmaf(v5.y,u1,a5); a5 = fmaf(v5.z,u2,a5); a5 = fmaf(v5.w,u3,a5);
                a6 = fmaf(v6.x,u0,a6); a6 = fmaf(v6.y,u1,a6); a6 = fmaf(v6.z,u2,a6); a6 = fmaf(v6.w,u3,a6);
                a7 = fmaf(v7.x,u0,a7); a7 = fmaf(v7.y,u1,a7); a7 = fmaf(v7.z,u2,a7); a7 = fmaf(v7.w,u3,a7);
            }
            if (g      < rv) mx = fmaxf(mx, a0);
            if (g +  2 < rv) mx = fmaxf(mx, a1);
            if (g +  4 < rv) mx = fmaxf(mx, a2);
            if (g +  6 < rv) mx = fmaxf(mx, a3);
            if (g +  8 < rv) mx = fmaxf(mx, a4);
            if (g + 10 < rv) mx = fmaxf(mx, a5);
            if (g + 12 < rv) mx = fmaxf(mx, a6);
            if (g + 14 < rv) mx = fmaxf(mx, a7);
        }
        __syncthreads();   // before next chunk overwrites A/Hs
    }

    // ---- combine groups, L2 normalize, store ----
    pmax[g][c] = mx;
    __syncthreads();
    float v = 0.f;
    if (g == 0) {
        v = fmaxf(pmax[0][c], pmax[1][c]);
        float s = (cnt > 0) ? v*v : 0.f;
        #pragma unroll
        for (int o = 32; o > 0; o >>= 1) s += __shfl_xor(s, o, 64);
        if (lane == 0) rsum[w] = s;
    }
    __syncthreads();
    if (g == 0) {
        float nrm = sqrtf(rsum[0] + rsum[1]);
        float o = (cnt > 0) ? v / fmaxf(nrm, 1e-12f) : 0.f;
        out[(size_t)m*HDIM + c] = o;
    }
}

extern "C" void kernel_launch(void* const* d_in, const int* in_sizes, int n_in,
                              void* d_out, int out_size, void* d_ws, size_t ws_size,
                              hipStream_t stream)
{
    const float* x       = (const float*)d_in[0];
    const float* pos     = (const float*)d_in[1];
    const float* W1      = (const float*)d_in[2];
    const float* b1      = (const float*)d_in[3];
    const float* W2      = (const float*)d_in[4];
    const float* b2      = (const float*)d_in[5];
    const int*   batch   = (const int*)d_in[6];
    const int*   key_idx = (const int*)d_in[7];

    int N = in_sizes[6];   // 100000
    int M = in_sizes[7];   // 2048

    desc_kernel<<<M, 256, 0, stream>>>(x, pos, W1, b1, W2, b2, batch, key_idx,
                                       (float*)d_out, N, M);
}

// Round 5
// 149.882 us; speedup vs baseline: 4.9551x; 3.1365x over previous
//
#include <hip/hip_runtime.h>
#include <math.h>

#define MAXK 64
#define HDIM 128
#define FDIM 64

typedef __attribute__((ext_vector_type(8))) short bf16x8;
typedef __attribute__((ext_vector_type(4))) float f32x4;

__device__ __forceinline__ unsigned short f2bf(float f) {
    unsigned x = __float_as_uint(f);
    unsigned r = (x + 0x7fffu + ((x >> 16) & 1u)) >> 16;   // RN-even
    return (unsigned short)r;
}

// ---------------------------------------------------------------------------
// K0: repack W1 [67][128] and W2 [128][128] (fp32) into bf16 MFMA B-fragment
// order in d_ws. B-frag for 16x16x32: lane l holds col=l&15, k=(l>>4)*8+j.
// Flat layout: [(cb*KS + ks)*64 + lane]*8 + j. W1 padded to K=96 with zeros.
// Re-run every launch (ws is re-poisoned to 0xAA by the harness).
// ---------------------------------------------------------------------------
__global__ __launch_bounds__(256) void prep_kernel(
    const float* __restrict__ W1, const float* __restrict__ W2,
    unsigned short* __restrict__ W1bf, unsigned short* __restrict__ W2bf)
{
    int t = blockIdx.x * 256 + threadIdx.x;
    if (t < 1536) {                       // W1: 8 cb * 3 ks * 64 lanes
        int s = t;
        int cb = s / 192, rem = s % 192, ks = rem / 64, lane = rem % 64;
        int col = cb*16 + (lane & 15);
        int k0  = ks*32 + (lane >> 4)*8;
        unsigned short v[8];
        #pragma unroll
        for (int j = 0; j < 8; ++j) {
            int k = k0 + j;
            v[j] = (k < 67) ? f2bf(W1[k*HDIM + col]) : (unsigned short)0;
        }
        uint4 p;
        p.x = (unsigned)v[0] | ((unsigned)v[1] << 16);
        p.y = (unsigned)v[2] | ((unsigned)v[3] << 16);
        p.z = (unsigned)v[4] | ((unsigned)v[5] << 16);
        p.w = (unsigned)v[6] | ((unsigned)v[7] << 16);
        *reinterpret_cast<uint4*>(&W1bf[(size_t)s*8]) = p;
    } else if (t < 1536 + 2048) {         // W2: 8 cb * 4 ks * 64 lanes
        int s = t - 1536;
        int cb = s >> 8, ks = (s >> 6) & 3, lane = s & 63;
        int col = cb*16 + (lane & 15);
        int k0  = ks*32 + (lane >> 4)*8;
        unsigned short v[8];
        #pragma unroll
        for (int j = 0; j < 8; ++j) v[j] = f2bf(W2[(k0+j)*HDIM + col]);
        uint4 p;
        p.x = (unsigned)v[0] | ((unsigned)v[1] << 16);
        p.y = (unsigned)v[2] | ((unsigned)v[3] << 16);
        p.z = (unsigned)v[4] | ((unsigned)v[5] << 16);
        p.w = (unsigned)v[6] | ((unsigned)v[7] << 16);
        *reinterpret_cast<uint4*>(&W2bf[(size_t)s*8]) = p;
    }
}

// ---------------------------------------------------------------------------
// K1: ball query, one 64-lane WAVE per (query, quarter-segment). Barrier-free,
// tiny VGPR -> max occupancy. Each quarter keeps its first <=64 hits in index
// order (global first-64 is a subset of the concatenation -> exact PyG
// semantics after the ordered merge in K2). d2 formula bit-matches reference.
// ---------------------------------------------------------------------------
__global__ __launch_bounds__(64) void scan_kernel(
    const float* __restrict__ pos, const int* __restrict__ batch,
    const int* __restrict__ key_idx, int N,
    int* __restrict__ lists, int* __restrict__ lcnt)
{
    int b = blockIdx.x;            // b = m*4 + w
    int m = b >> 2, w = b & 3;
    int lane = threadIdx.x;

    int qi = key_idx[m];
    int qb = batch[qi];
    float qx = pos[3*qi+0], qy = pos[3*qi+1], qz = pos[3*qi+2];

    int lo, hi;
    { int a=0, e=N;  while (a<e){ int mid=(a+e)>>1; if (batch[mid] <  qb) a=mid+1; else e=mid; } lo=a; }
    { int a=lo, e=N; while (a<e){ int mid=(a+e)>>1; if (batch[mid] <= qb) a=mid+1; else e=mid; } hi=a; }

    // (float)0.04 != 0.2f*0.2f (1 ulp). Keep exact reference arithmetic,
    // no fma contraction — neighbor CLASSIFICATION must stay bit-exact.
    const float R2 = 0.04f;
    float q2 = __fadd_rn(__fadd_rn(__fmul_rn(qx,qx), __fmul_rn(qy,qy)), __fmul_rn(qz,qz));

    int seg   = hi - lo;
    int qlen  = (seg + 3) >> 2;
    int start = lo + w*qlen;
    int qend  = min(start + qlen, hi);

    int lc = 0;
    for (int base = start; base < qend && lc < MAXK; base += 256) {
        unsigned long long mk[4]; bool vv[4]; int jj[4];
        #pragma unroll
        for (int sub = 0; sub < 4; ++sub) {
            int j = base + sub*64 + lane;
            bool v = false;
            if (j < qend) {
                float px = pos[3*j+0], py = pos[3*j+1], pz = pos[3*j+2];
                float p2 = __fadd_rn(__fadd_rn(__fmul_rn(px,px), __fmul_rn(py,py)), __fmul_rn(pz,pz));
                float dt = __fadd_rn(__fadd_rn(__fmul_rn(qx,px), __fmul_rn(qy,py)), __fmul_rn(qz,pz));
                float d2 = __fsub_rn(__fadd_rn(q2, p2), __fmul_rn(2.0f, dt));
                v = (d2 <= R2);
            }
            mk[sub] = __ballot(v); vv[sub] = v; jj[sub] = j;
        }
        #pragma unroll
        for (int sub = 0; sub < 4; ++sub) {
            if (vv[sub]) {
                int slot = lc + (int)__popcll(mk[sub] & ((1ull << lane) - 1ull));
                if (slot < MAXK) lists[b*MAXK + slot] = jj[sub];
            }
            lc += (int)__popcll(mk[sub]);
        }
    }
    if (lane == 0) lcnt[b] = min(lc, MAXK);
}

// ---------------------------------------------------------------------------
// K2: MFMA MLP. One 256-thread block (4 waves) per query.
//  - merge quarter lists -> nidx[64], cnt
//  - stage A [64 rows x 96 k] bf16 DIRECTLY in A-fragment layout in LDS
//    (lane-linear 16B slots -> conflict-free ds_read_b128/ds_write_b128)
//  - wave w owns row-block w (rows w*16..w*16+15):
//    layer1: 8 col-blocks x 3 ksteps mfma_f32_16x16x32_bf16, +b1, relu,
//            bf16 -> H in XOR-swizzled LDS (G4: row-major [16][128] bf16)
//    layer2: 8 col-blocks x 4 ksteps, +b2, row<cnt masked max
//  - cross-lane/wave max, L2 normalize, store.
// C/D layout (m89-verified): col=lane&15, row=(lane>>4)*4+reg.
// A-frag: row=lane&15, k=(lane>>4)*8+j.  B-frag: col=lane&15, k=(lane>>4)*8+j.
// ---------------------------------------------------------------------------
__global__ __launch_bounds__(256) void mlp_kernel(
    const float* __restrict__ x, const float* __restrict__ pos,
    const unsigned short* __restrict__ W1bf, const unsigned short* __restrict__ W2bf,
    const float* __restrict__ b1, const float* __restrict__ b2,
    const int* __restrict__ key_idx,
    const int* __restrict__ lists, const int* __restrict__ lcnt,
    float* __restrict__ out, int M)
{
    __shared__ __align__(16) unsigned short a_lds[4*3*64*8];   // 12 KB
    __shared__ __align__(16) unsigned short h_lds[4*16*128];   // 16 KB
    __shared__ int   nidx[MAXK];
    __shared__ float pmax_s[4][HDIM];                          // 2 KB
    __shared__ float rsum[2];

    int m   = blockIdx.x;
    int tid = threadIdx.x;
    int lane = tid & 63, w = tid >> 6;
    int colq = lane & 15, rq = lane >> 4;

    int qi = key_idx[m];
    float qx = pos[3*qi+0], qy = pos[3*qi+1], qz = pos[3*qi+2];

    // ---- ordered merge of the 4 quarter lists ----
    int c0 = lcnt[m*4+0], c1 = lcnt[m*4+1], c2 = lcnt[m*4+2], c3 = lcnt[m*4+3];
    int cnt = min(MAXK, c0 + c1 + c2 + c3);
    if (tid < cnt) {
        int k = tid, q, off;
        if      (k < c0)       { q = 0; off = k; }
        else if (k < c0+c1)    { q = 1; off = k - c0; }
        else if (k < c0+c1+c2) { q = 2; off = k - c0 - c1; }
        else                   { q = 3; off = k - c0 - c1 - c2; }
        nidx[tid] = lists[(m*4+q)*MAXK + off];
    }
    __syncthreads();

    // ---- stage A fragments: 768 slots (rb,ks,lane), 3 per thread ----
    #pragma unroll
    for (int i = 0; i < 3; ++i) {
        int s = tid + i*256;
        int rb = s / 192, rem = s % 192, ks = rem / 64, ln = rem % 64;
        int row = rb*16 + (ln & 15);
        int k0  = ks*32 + (ln >> 4)*8;
        unsigned short v[8];
        #pragma unroll
        for (int j = 0; j < 8; ++j) v[j] = 0;
        if (row < cnt) {
            int idx = nidx[row];
            if (ks < 2) {                 // k0..k0+7 all < 64 -> x row
                const float4* xp = reinterpret_cast<const float4*>(x + (size_t)idx*FDIM + k0);
                float4 v0 = xp[0], v1 = xp[1];
                v[0]=f2bf(v0.x); v[1]=f2bf(v0.y); v[2]=f2bf(v0.z); v[3]=f2bf(v0.w);
                v[4]=f2bf(v1.x); v[5]=f2bf(v1.y); v[6]=f2bf(v1.z); v[7]=f2bf(v1.w);
            } else if ((ln >> 4) == 0) {  // k0==64 -> rel, rest 0
                v[0] = f2bf(pos[3*idx+0] - qx);
                v[1] = f2bf(pos[3*idx+1] - qy);
                v[2] = f2bf(pos[3*idx+2] - qz);
            }
        }
        uint4 p;
        p.x = (unsigned)v[0] | ((unsigned)v[1] << 16);
        p.y = (unsigned)v[2] | ((unsigned)v[3] << 16);
        p.z = (unsigned)v[4] | ((unsigned)v[5] << 16);
        p.w = (unsigned)v[6] | ((unsigned)v[7] << 16);
        *reinterpret_cast<uint4*>(&a_lds[(size_t)s*8]) = p;
    }
    __syncthreads();

    const bf16x8* W1f = reinterpret_cast<const bf16x8*>(W1bf);
    const bf16x8* W2f = reinterpret_cast<const bf16x8*>(W2bf);

    // ---- layer 1: wave w = row-block w ----
    bf16x8 a0 = *reinterpret_cast<const bf16x8*>(&a_lds[((w*3+0)*64 + lane)*8]);
    bf16x8 a1 = *reinterpret_cast<const bf16x8*>(&a_lds[((w*3+1)*64 + lane)*8]);
    bf16x8 a2 = *reinterpret_cast<const bf16x8*>(&a_lds[((w*3+2)*64 + lane)*8]);
    #pragma unroll
    for (int cb = 0; cb < 8; ++cb) {
        f32x4 c = {0.f, 0.f, 0.f, 0.f};
        c = __builtin_amdgcn_mfma_f32_16x16x32_bf16(a0, W1f[(cb*3+0)*64 + lane], c, 0, 0, 0);
        c = __builtin_amdgcn_mfma_f32_16x16x32_bf16(a1, W1f[(cb*3+1)*64 + lane], c, 0, 0, 0);
        c = __builtin_amdgcn_mfma_f32_16x16x32_bf16(a2, W1f[(cb*3+2)*64 + lane], c, 0, 0, 0);
        int col = cb*16 + colq;
        float bias = b1[col];
        #pragma unroll
        for (int reg = 0; reg < 4; ++reg) {
            int r = rq*4 + reg;
            float h = fmaxf(c[reg] + bias, 0.f);
            // XOR-swizzled row-major [16][128] bf16 (ushort-index swizzle <<3)
            h_lds[w*2048 + r*128 + (col ^ ((r & 7) << 3))] = f2bf(h);
        }
    }
    // wave-local LDS RAW (wave w wrote & reads only row-block w): no barrier.

    // ---- layer 2 ----
    int r = colq, swz = (r & 7) << 3;
    bf16x8 g0 = *reinterpret_cast<const bf16x8*>(&h_lds[w*2048 + r*128 + ((  0 + rq*8) ^ swz)]);
    bf16x8 g1 = *reinterpret_cast<const bf16x8*>(&h_lds[w*2048 + r*128 + (( 32 + rq*8) ^ swz)]);
    bf16x8 g2 = *reinterpret_cast<const bf16x8*>(&h_lds[w*2048 + r*128 + (( 64 + rq*8) ^ swz)]);
    bf16x8 g3 = *reinterpret_cast<const bf16x8*>(&h_lds[w*2048 + r*128 + (( 96 + rq*8) ^ swz)]);
    #pragma unroll
    for (int cb = 0; cb < 8; ++cb) {
        f32x4 c = {0.f, 0.f, 0.f, 0.f};
        c = __builtin_amdgcn_mfma_f32_16x16x32_bf16(g0, W2f[(cb*4+0)*64 + lane], c, 0, 0, 0);
        c = __builtin_amdgcn_mfma_f32_16x16x32_bf16(g1, W2f[(cb*4+1)*64 + lane], c, 0, 0, 0);
        c = __builtin_amdgcn_mfma_f32_16x16x32_bf16(g2, W2f[(cb*4+2)*64 + lane], c, 0, 0, 0);
        c = __builtin_amdgcn_mfma_f32_16x16x32_bf16(g3, W2f[(cb*4+3)*64 + lane], c, 0, 0, 0);
        int col = cb*16 + colq;
        float bias = b2[col];
        float mx = -INFINITY;
        #pragma unroll
        for (int reg = 0; reg < 4; ++reg) {
            int row = w*16 + rq*4 + reg;
            float val = c[reg] + bias;
            if (row < cnt) mx = fmaxf(mx, val);
        }
        mx = fmaxf(mx, __shfl_xor(mx, 16, 64));   // reduce over rq
        mx = fmaxf(mx, __shfl_xor(mx, 32, 64));
        if (rq == 0) pmax_s[w][col] = mx;
    }
    __syncthreads();

    // ---- combine row-blocks, L2 normalize, store ----
    int c = tid & 127, g = tid >> 7;
    float v = fmaxf(fmaxf(pmax_s[0][c], pmax_s[1][c]),
                    fmaxf(pmax_s[2][c], pmax_s[3][c]));
    if (cnt == 0) v = 0.f;
    float s = (g == 0) ? v*v : 0.f;
    #pragma unroll
    for (int o = 32; o > 0; o >>= 1) s += __shfl_xor(s, o, 64);
    if (g == 0 && (tid & 63) == 0) rsum[tid >> 6] = s;
    __syncthreads();
    if (g == 0) {
        float nrm = fmaxf(sqrtf(rsum[0] + rsum[1]), 1e-12f);
        out[(size_t)m*HDIM + c] = v / nrm;
    }
}

extern "C" void kernel_launch(void* const* d_in, const int* in_sizes, int n_in,
                              void* d_out, int out_size, void* d_ws, size_t ws_size,
                              hipStream_t stream)
{
    const float* x       = (const float*)d_in[0];
    const float* pos     = (const float*)d_in[1];
    const float* W1      = (const float*)d_in[2];
    const float* b1      = (const float*)d_in[3];
    const float* W2      = (const float*)d_in[4];
    const float* b2      = (const float*)d_in[5];
    const int*   batch   = (const int*)d_in[6];
    const int*   key_idx = (const int*)d_in[7];

    int N = in_sizes[6];   // 100000
    int M = in_sizes[7];   // 2048

    unsigned short* W1bf = (unsigned short*)d_ws;                 // 12288 ushort
    unsigned short* W2bf = W1bf + 12288;                          // 16384 ushort
    int* lists = (int*)(W2bf + 16384);                            // M*4*64 ints
    int* lcnt  = lists + (size_t)M * 4 * MAXK;                    // M*4 ints

    prep_kernel<<<14, 256, 0, stream>>>(W1, W2, W1bf, W2bf);
    scan_kernel<<<M*4, 64, 0, stream>>>(pos, batch, key_idx, N, lists, lcnt);
    mlp_kernel<<<M, 256, 0, stream>>>(x, pos, W1bf, W2bf, b1, b2, key_idx,
                                      lists, lcnt, (float*)d_out, M);
}

// Round 6
// 148.075 us; speedup vs baseline: 5.0155x; 1.0122x over previous
//
#include <hip/hip_runtime.h>
#include <math.h>

#define MAXK 64
#define HDIM 128
#define FDIM 64

typedef __attribute__((ext_vector_type(8))) short bf16x8;
typedef __attribute__((ext_vector_type(4))) float f32x4;

__device__ __forceinline__ unsigned short f2bf(float f) {
    unsigned x = __float_as_uint(f);
    unsigned r = (x + 0x7fffu + ((x >> 16) & 1u)) >> 16;   // RN-even
    return (unsigned short)r;
}
__device__ __forceinline__ unsigned pk2(float a, float b) {
    return (unsigned)f2bf(a) | ((unsigned)f2bf(b) << 16);
}

// ---------------------------------------------------------------------------
// K0: repack W1/W2 (fp32) -> bf16 MFMA B-fragment order, and pos -> posq
// float4 {x,y,z,p2}. p2 uses the EXACT reference formula (same ops/order as
// the per-candidate computation it replaces -> bit-identical classification).
// Re-run every launch (ws is re-poisoned).
// B-frag 16x16x32: lane l holds col=l&15, k=(l>>4)*8+j.
// ---------------------------------------------------------------------------
__global__ __launch_bounds__(256) void prep_kernel(
    const float* __restrict__ W1, const float* __restrict__ W2,
    const float* __restrict__ pos, int N,
    unsigned short* __restrict__ W1bf, unsigned short* __restrict__ W2bf,
    float4* __restrict__ posq)
{
    int t = blockIdx.x * 256 + threadIdx.x;
    if (t < 1536) {                       // W1: 8 cb * 3 ks * 64 lanes
        int s = t;
        int cb = s / 192, rem = s % 192, ks = rem / 64, lane = rem % 64;
        int col = cb*16 + (lane & 15);
        int k0  = ks*32 + (lane >> 4)*8;
        unsigned short v[8];
        #pragma unroll
        for (int j = 0; j < 8; ++j) {
            int k = k0 + j;
            v[j] = (k < 67) ? f2bf(W1[k*HDIM + col]) : (unsigned short)0;
        }
        uint4 p;
        p.x = (unsigned)v[0] | ((unsigned)v[1] << 16);
        p.y = (unsigned)v[2] | ((unsigned)v[3] << 16);
        p.z = (unsigned)v[4] | ((unsigned)v[5] << 16);
        p.w = (unsigned)v[6] | ((unsigned)v[7] << 16);
        *reinterpret_cast<uint4*>(&W1bf[(size_t)s*8]) = p;
    } else if (t < 1536 + 2048) {         // W2: 8 cb * 4 ks * 64 lanes
        int s = t - 1536;
        int cb = s >> 8, ks = (s >> 6) & 3, lane = s & 63;
        int col = cb*16 + (lane & 15);
        int k0  = ks*32 + (lane >> 4)*8;
        unsigned short v[8];
        #pragma unroll
        for (int j = 0; j < 8; ++j) v[j] = f2bf(W2[(k0+j)*HDIM + col]);
        uint4 p;
        p.x = (unsigned)v[0] | ((unsigned)v[1] << 16);
        p.y = (unsigned)v[2] | ((unsigned)v[3] << 16);
        p.z = (unsigned)v[4] | ((unsigned)v[5] << 16);
        p.w = (unsigned)v[6] | ((unsigned)v[7] << 16);
        *reinterpret_cast<uint4*>(&W2bf[(size_t)s*8]) = p;
    } else {
        int i = t - 3584;
        if (i < N) {
            float px = pos[3*i+0], py = pos[3*i+1], pz = pos[3*i+2];
            float p2 = __fadd_rn(__fadd_rn(__fmul_rn(px,px), __fmul_rn(py,py)), __fmul_rn(pz,pz));
            posq[i] = make_float4(px, py, pz, p2);
        }
    }
}

// ---------------------------------------------------------------------------
// K1: ball query, one wave per (query, quarter-segment). Barrier-free.
// Per candidate: ONE coalesced dwordx4 {x,y,z,p2} + dt/d2 in the exact
// reference arithmetic (no fma contraction). Quarter lists keep first <=64
// hits in index order -> ordered merge in K2 == exact PyG semantics.
// ---------------------------------------------------------------------------
__global__ __launch_bounds__(64) void scan_kernel(
    const float4* __restrict__ posq, const int* __restrict__ batch,
    const int* __restrict__ key_idx, int N,
    int* __restrict__ lists, int* __restrict__ lcnt)
{
    int b = blockIdx.x;            // b = m*4 + w
    int m = b >> 2, w = b & 3;
    int lane = threadIdx.x;

    int qi = key_idx[m];
    int qb = batch[qi];
    float4 q4 = posq[qi];
    float qx = q4.x, qy = q4.y, qz = q4.z, q2 = q4.w;

    int lo, hi;
    { int a=0, e=N;  while (a<e){ int mid=(a+e)>>1; if (batch[mid] <  qb) a=mid+1; else e=mid; } lo=a; }
    { int a=lo, e=N; while (a<e){ int mid=(a+e)>>1; if (batch[mid] <= qb) a=mid+1; else e=mid; } hi=a; }

    // (float)0.04 != 0.2f*0.2f (1 ulp). Classification must stay bit-exact.
    const float R2 = 0.04f;

    int seg   = hi - lo;
    int qlen  = (seg + 3) >> 2;
    int start = lo + w*qlen;
    int qend  = min(start + qlen, hi);

    int lc = 0;
    for (int base = start; base < qend && lc < MAXK; base += 256) {
        unsigned long long mk[4]; bool vv[4]; int jj[4];
        #pragma unroll
        for (int sub = 0; sub < 4; ++sub) {
            int j = base + sub*64 + lane;
            bool v = false;
            if (j < qend) {
                float4 p = posq[j];
                float dt = __fadd_rn(__fadd_rn(__fmul_rn(qx,p.x), __fmul_rn(qy,p.y)), __fmul_rn(qz,p.z));
                float d2 = __fsub_rn(__fadd_rn(q2, p.w), __fmul_rn(2.0f, dt));
                v = (d2 <= R2);
            }
            mk[sub] = __ballot(v); vv[sub] = v; jj[sub] = j;
        }
        #pragma unroll
        for (int sub = 0; sub < 4; ++sub) {
            if (vv[sub]) {
                int slot = lc + (int)__popcll(mk[sub] & ((1ull << lane) - 1ull));
                if (slot < MAXK) lists[b*MAXK + slot] = jj[sub];
            }
            lc += (int)__popcll(mk[sub]);
        }
    }
    if (lane == 0) lcnt[b] = min(lc, MAXK);
}

// ---------------------------------------------------------------------------
// K2: MFMA MLP. One 256-thread block (4 waves) per query.
//  - merge quarter lists -> nidx[64], cnt
//  - A-fragments gathered DIRECTLY to registers (no a_lds, no extra barrier):
//    lane of wave w holds row=w*16+(lane&15); k-slice rq*8 via 2x float4 from x.
//  - layer1: 8 cb x 3 ksteps mfma_f32_16x16x32_bf16, +b1, relu, bf16 ->
//    XOR-swizzled wave-local h_lds; layer2: 8 cb x 4 ksteps, masked max.
//  - cross-lane/wave max, L2 normalize, store.
// C/D layout (m89): col=lane&15, row=(lane>>4)*4+reg.
// A-frag: row=lane&15, k=(lane>>4)*8+j.  B-frag: col=lane&15, k=(lane>>4)*8+j.
// ---------------------------------------------------------------------------
__global__ __launch_bounds__(256) void mlp_kernel(
    const float* __restrict__ x, const float4* __restrict__ posq,
    const unsigned short* __restrict__ W1bf, const unsigned short* __restrict__ W2bf,
    const float* __restrict__ b1, const float* __restrict__ b2,
    const int* __restrict__ key_idx,
    const int* __restrict__ lists, const int* __restrict__ lcnt,
    float* __restrict__ out, int M)
{
    __shared__ __align__(16) unsigned short h_lds[4*16*128];   // 16 KB
    __shared__ int   nidx[MAXK];
    __shared__ float pmax_s[4][HDIM];                          // 2 KB
    __shared__ float rsum[2];

    int m   = blockIdx.x;
    int tid = threadIdx.x;
    int lane = tid & 63, w = tid >> 6;
    int colq = lane & 15, rq = lane >> 4;

    int qi = key_idx[m];
    float4 q4 = posq[qi];

    // ---- ordered merge of the 4 quarter lists ----
    int c0 = lcnt[m*4+0], c1 = lcnt[m*4+1], c2 = lcnt[m*4+2], c3 = lcnt[m*4+3];
    int cnt = min(MAXK, c0 + c1 + c2 + c3);
    if (tid < cnt) {
        int k = tid, q, off;
        if      (k < c0)       { q = 0; off = k; }
        else if (k < c0+c1)    { q = 1; off = k - c0; }
        else if (k < c0+c1+c2) { q = 2; off = k - c0 - c1; }
        else                   { q = 3; off = k - c0 - c1 - c2; }
        nidx[tid] = lists[(m*4+q)*MAXK + off];
    }
    __syncthreads();

    // ---- direct register A-fragment gather (row = w*16 + colq) ----
    int row = w*16 + colq;
    union { bf16x8 v; uint4 u; } A0, A1, A2;
    A0.u = make_uint4(0,0,0,0); A1.u = A0.u; A2.u = A0.u;
    if (row < cnt) {
        int idx = nidx[row];
        const float4* xp = reinterpret_cast<const float4*>(x + (size_t)idx*FDIM + rq*8);
        float4 u0 = xp[0], u1 = xp[1];
        const float4* xq = reinterpret_cast<const float4*>(x + (size_t)idx*FDIM + 32 + rq*8);
        float4 u2 = xq[0], u3 = xq[1];
        A0.u.x = pk2(u0.x, u0.y); A0.u.y = pk2(u0.z, u0.w);
        A0.u.z = pk2(u1.x, u1.y); A0.u.w = pk2(u1.z, u1.w);
        A1.u.x = pk2(u2.x, u2.y); A1.u.y = pk2(u2.z, u2.w);
        A1.u.z = pk2(u3.x, u3.y); A1.u.w = pk2(u3.z, u3.w);
        if (rq == 0) {                       // k=64..66 -> rel, rest 0
            float4 p = posq[idx];
            A2.u.x = pk2(p.x - q4.x, p.y - q4.y);
            A2.u.y = pk2(p.z - q4.z, 0.f);
        }
    }

    const bf16x8* W1f = reinterpret_cast<const bf16x8*>(W1bf);
    const bf16x8* W2f = reinterpret_cast<const bf16x8*>(W2bf);

    // ---- layer 1 ----
    #pragma unroll
    for (int cb = 0; cb < 8; ++cb) {
        f32x4 c = {0.f, 0.f, 0.f, 0.f};
        c = __builtin_amdgcn_mfma_f32_16x16x32_bf16(A0.v, W1f[(cb*3+0)*64 + lane], c, 0, 0, 0);
        c = __builtin_amdgcn_mfma_f32_16x16x32_bf16(A1.v, W1f[(cb*3+1)*64 + lane], c, 0, 0, 0);
        c = __builtin_amdgcn_mfma_f32_16x16x32_bf16(A2.v, W1f[(cb*3+2)*64 + lane], c, 0, 0, 0);
        int col = cb*16 + colq;
        float bias = b1[col];
        #pragma unroll
        for (int reg = 0; reg < 4; ++reg) {
            int r = rq*4 + reg;
            float h = fmaxf(c[reg] + bias, 0.f);
            // XOR-swizzled row-major [16][128] bf16 (ushort-index swizzle <<3)
            h_lds[w*2048 + r*128 + (col ^ ((r & 7) << 3))] = f2bf(h);
        }
    }
    // wave-local LDS RAW (wave w wrote & reads only its block): no barrier.

    // ---- layer 2 ----
    int r = colq, swz = (r & 7) << 3;
    bf16x8 g0 = *reinterpret_cast<const bf16x8*>(&h_lds[w*2048 + r*128 + ((  0 + rq*8) ^ swz)]);
    bf16x8 g1 = *reinterpret_cast<const bf16x8*>(&h_lds[w*2048 + r*128 + (( 32 + rq*8) ^ swz)]);
    bf16x8 g2 = *reinterpret_cast<const bf16x8*>(&h_lds[w*2048 + r*128 + (( 64 + rq*8) ^ swz)]);
    bf16x8 g3 = *reinterpret_cast<const bf16x8*>(&h_lds[w*2048 + r*128 + (( 96 + rq*8) ^ swz)]);
    #pragma unroll
    for (int cb = 0; cb < 8; ++cb) {
        f32x4 c = {0.f, 0.f, 0.f, 0.f};
        c = __builtin_amdgcn_mfma_f32_16x16x32_bf16(g0, W2f[(cb*4+0)*64 + lane], c, 0, 0, 0);
        c = __builtin_amdgcn_mfma_f32_16x16x32_bf16(g1, W2f[(cb*4+1)*64 + lane], c, 0, 0, 0);
        c = __builtin_amdgcn_mfma_f32_16x16x32_bf16(g2, W2f[(cb*4+2)*64 + lane], c, 0, 0, 0);
        c = __builtin_amdgcn_mfma_f32_16x16x32_bf16(g3, W2f[(cb*4+3)*64 + lane], c, 0, 0, 0);
        int col = cb*16 + colq;
        float bias = b2[col];
        float mx = -INFINITY;
        #pragma unroll
        for (int reg = 0; reg < 4; ++reg) {
            int rr = w*16 + rq*4 + reg;
            float val = c[reg] + bias;
            if (rr < cnt) mx = fmaxf(mx, val);
        }
        mx = fmaxf(mx, __shfl_xor(mx, 16, 64));   // reduce over rq
        mx = fmaxf(mx, __shfl_xor(mx, 32, 64));
        if (rq == 0) pmax_s[w][col] = mx;
    }
    __syncthreads();

    // ---- combine row-blocks, L2 normalize, store ----
    int c = tid & 127, g = tid >> 7;
    float v = fmaxf(fmaxf(pmax_s[0][c], pmax_s[1][c]),
                    fmaxf(pmax_s[2][c], pmax_s[3][c]));
    if (cnt == 0) v = 0.f;
    float s = (g == 0) ? v*v : 0.f;
    #pragma unroll
    for (int o = 32; o > 0; o >>= 1) s += __shfl_xor(s, o, 64);
    if (g == 0 && (tid & 63) == 0) rsum[tid >> 6] = s;
    __syncthreads();
    if (g == 0) {
        float nrm = fmaxf(sqrtf(rsum[0] + rsum[1]), 1e-12f);
        out[(size_t)m*HDIM + c] = v / nrm;
    }
}

extern "C" void kernel_launch(void* const* d_in, const int* in_sizes, int n_in,
                              void* d_out, int out_size, void* d_ws, size_t ws_size,
                              hipStream_t stream)
{
    const float* x       = (const float*)d_in[0];
    const float* pos     = (const float*)d_in[1];
    const float* W1      = (const float*)d_in[2];
    const float* b1      = (const float*)d_in[3];
    const float* W2      = (const float*)d_in[4];
    const float* b2      = (const float*)d_in[5];
    const int*   batch   = (const int*)d_in[6];
    const int*   key_idx = (const int*)d_in[7];

    int N = in_sizes[6];   // 100000
    int M = in_sizes[7];   // 2048

    unsigned short* W1bf = (unsigned short*)d_ws;                 // 24 KB
    unsigned short* W2bf = W1bf + 12288;                          // 32 KB
    float4* posq = (float4*)(W2bf + 16384);                       // N*16 B
    int* lists = (int*)(posq + N);                                // M*4*64 ints
    int* lcnt  = lists + (size_t)M * 4 * MAXK;                    // M*4 ints

    int prep_blocks = (3584 + N + 255) / 256;
    prep_kernel<<<prep_blocks, 256, 0, stream>>>(W1, W2, pos, N, W1bf, W2bf, posq);
    scan_kernel<<<M*4, 64, 0, stream>>>(posq, batch, key_idx, N, lists, lcnt);
    mlp_kernel<<<M, 256, 0, stream>>>(x, posq, W1bf, W2bf, b1, b2, key_idx,
                                      lists, lcnt, (float*)d_out, M);
}

// Round 7
// 143.384 us; speedup vs baseline: 5.1796x; 1.0327x over previous
//
#include <hip/hip_runtime.h>
#include <math.h>

#define MAXK 64
#define HDIM 128
#define FDIM 64
#define NSPLIT 16

typedef __attribute__((ext_vector_type(8))) short bf16x8;
typedef __attribute__((ext_vector_type(4))) float f32x4;

__device__ __forceinline__ unsigned short f2bf(float f) {
    unsigned x = __float_as_uint(f);
    unsigned r = (x + 0x7fffu + ((x >> 16) & 1u)) >> 16;   // RN-even
    return (unsigned short)r;
}
__device__ __forceinline__ unsigned pk2(float a, float b) {
    return (unsigned)f2bf(a) | ((unsigned)f2bf(b) << 16);
}

// ---------------------------------------------------------------------------
// K0: repack W1/W2 -> bf16 B-fragment order; pos -> posq {x,y,z,p2} (exact
// reference formula -> bit-identical classification); batch segment bounds
// bounds[v] = lower_bound(batch, v), v in [0,4] (batch values are 0..3).
// Re-run every launch (ws re-poisoned). B-frag 16x16x32: lane l holds
// col=l&15, k=(l>>4)*8+j.
// ---------------------------------------------------------------------------
__global__ __launch_bounds__(256) void prep_kernel(
    const float* __restrict__ W1, const float* __restrict__ W2,
    const float* __restrict__ pos, const int* __restrict__ batch, int N,
    unsigned short* __restrict__ W1bf, unsigned short* __restrict__ W2bf,
    float4* __restrict__ posq, int* __restrict__ bounds)
{
    int t = blockIdx.x * 256 + threadIdx.x;
    if (t < 1536) {                       // W1: 8 cb * 3 ks * 64 lanes
        int s = t;
        int cb = s / 192, rem = s % 192, ks = rem / 64, lane = rem % 64;
        int col = cb*16 + (lane & 15);
        int k0  = ks*32 + (lane >> 4)*8;
        unsigned short v[8];
        #pragma unroll
        for (int j = 0; j < 8; ++j) {
            int k = k0 + j;
            v[j] = (k < 67) ? f2bf(W1[k*HDIM + col]) : (unsigned short)0;
        }
        uint4 p;
        p.x = (unsigned)v[0] | ((unsigned)v[1] << 16);
        p.y = (unsigned)v[2] | ((unsigned)v[3] << 16);
        p.z = (unsigned)v[4] | ((unsigned)v[5] << 16);
        p.w = (unsigned)v[6] | ((unsigned)v[7] << 16);
        *reinterpret_cast<uint4*>(&W1bf[(size_t)s*8]) = p;
    } else if (t < 3584) {                // W2: 8 cb * 4 ks * 64 lanes
        int s = t - 1536;
        int cb = s >> 8, ks = (s >> 6) & 3, lane = s & 63;
        int col = cb*16 + (lane & 15);
        int k0  = ks*32 + (lane >> 4)*8;
        unsigned short v[8];
        #pragma unroll
        for (int j = 0; j < 8; ++j) v[j] = f2bf(W2[(k0+j)*HDIM + col]);
        uint4 p;
        p.x = (unsigned)v[0] | ((unsigned)v[1] << 16);
        p.y = (unsigned)v[2] | ((unsigned)v[3] << 16);
        p.z = (unsigned)v[4] | ((unsigned)v[5] << 16);
        p.w = (unsigned)v[6] | ((unsigned)v[7] << 16);
        *reinterpret_cast<uint4*>(&W2bf[(size_t)s*8]) = p;
    } else if (t < 3584 + N) {
        int i = t - 3584;
        float px = pos[3*i+0], py = pos[3*i+1], pz = pos[3*i+2];
        float p2 = __fadd_rn(__fadd_rn(__fmul_rn(px,px), __fmul_rn(py,py)), __fmul_rn(pz,pz));
        posq[i] = make_float4(px, py, pz, p2);
    } else if (t < 3584 + N + 5) {
        int v = t - 3584 - N;             // bounds[v] = lower_bound(batch, v)
        int a = 0, e = N;
        while (a < e) { int mid = (a+e) >> 1; if (batch[mid] < v) a = mid+1; else e = mid; }
        bounds[v] = a;
    }
}

// ---------------------------------------------------------------------------
// K1: ball query, one wave per (query, 1/16-segment). Barrier-free. Segment
// bounds precomputed. Per candidate: ONE dwordx4 + exact reference d2 (no fma
// contraction). Each split keeps its first <=64 hits in index order; splits
// are contiguous ranges -> first-64 of ordered concat == exact PyG.
// ---------------------------------------------------------------------------
__global__ __launch_bounds__(64) void scan_kernel(
    const float4* __restrict__ posq, const int* __restrict__ batch,
    const int* __restrict__ key_idx, const int* __restrict__ bounds,
    int* __restrict__ lists, int* __restrict__ lcnt)
{
    int b = blockIdx.x;            // b = m*NSPLIT + w
    int m = b >> 4, w = b & 15;
    int lane = threadIdx.x;

    int qi = key_idx[m];
    int qb = batch[qi];
    float4 q4 = posq[qi];
    float qx = q4.x, qy = q4.y, qz = q4.z, q2 = q4.w;

    int lo = bounds[qb], hi = bounds[qb+1];

    // (float)0.04 != 0.2f*0.2f (1 ulp). Classification must stay bit-exact.
    const float R2 = 0.04f;

    int seg   = hi - lo;
    int qlen  = (seg + NSPLIT - 1) >> 4;
    int start = lo + w*qlen;
    int qend  = min(start + qlen, hi);

    int lc = 0;
    for (int base = start; base < qend && lc < MAXK; base += 256) {
        unsigned long long mk[4]; bool vv[4]; int jj[4];
        #pragma unroll
        for (int sub = 0; sub < 4; ++sub) {
            int j = base + sub*64 + lane;
            bool v = false;
            if (j < qend) {
                float4 p = posq[j];
                float dt = __fadd_rn(__fadd_rn(__fmul_rn(qx,p.x), __fmul_rn(qy,p.y)), __fmul_rn(qz,p.z));
                float d2 = __fsub_rn(__fadd_rn(q2, p.w), __fmul_rn(2.0f, dt));
                v = (d2 <= R2);
            }
            mk[sub] = __ballot(v); vv[sub] = v; jj[sub] = j;
        }
        #pragma unroll
        for (int sub = 0; sub < 4; ++sub) {
            if (vv[sub]) {
                int slot = lc + (int)__popcll(mk[sub] & ((1ull << lane) - 1ull));
                if (slot < MAXK) lists[b*MAXK + slot] = jj[sub];
            }
            lc += (int)__popcll(mk[sub]);
        }
    }
    if (lane == 0) lcnt[b] = min(lc, MAXK);
}

// ---------------------------------------------------------------------------
// K2: MFMA MLP. One 256-thread block (4 waves) per query. Barrier-free until
// the final cross-wave combine:
//  - each lane locates its row's (split,offset) via 16-step prefix over lcnt
//    (uniform scalar loads) and reads lists directly -> no nidx LDS, no merge
//    barrier; x-gather issues immediately.
//  - A-fragments in registers: lane holds row=w*16+(lane&15), k-slice rq*8.
//  - layer1: 8 cb x 3 ksteps mfma_16x16x32_bf16, +b1, relu -> XOR-swizzled
//    wave-local h_lds; layer2: 8 cb x 4 ksteps, row<cnt masked max.
// C/D (m89): col=lane&15, row=(lane>>4)*4+reg. A/B-frag: k=(lane>>4)*8+j.
// ---------------------------------------------------------------------------
__global__ __launch_bounds__(256) void mlp_kernel(
    const float* __restrict__ x, const float4* __restrict__ posq,
    const unsigned short* __restrict__ W1bf, const unsigned short* __restrict__ W2bf,
    const float* __restrict__ b1, const float* __restrict__ b2,
    const int* __restrict__ key_idx,
    const int* __restrict__ lists, const int* __restrict__ lcnt,
    float* __restrict__ out, int M)
{
    __shared__ __align__(16) unsigned short h_lds[4*16*128];   // 16 KB
    __shared__ float pmax_s[4][HDIM];                          // 2 KB
    __shared__ float rsum[2];

    int m   = blockIdx.x;
    int tid = threadIdx.x;
    int lane = tid & 63, w = tid >> 6;
    int colq = lane & 15, rq = lane >> 4;

    int qi = key_idx[m];
    float4 q4 = posq[qi];

    // ---- per-lane ordered-merge lookup: row -> (split, offset) ----
    int row = w*16 + colq;
    int cnt = 0, src = -1;
    #pragma unroll
    for (int t = 0; t < NSPLIT; ++t) {
        int ct = lcnt[m*NSPLIT + t];
        if (row >= cnt && row - cnt < ct) src = (m*NSPLIT + t)*MAXK + (row - cnt);
        cnt += ct;
    }
    if (cnt > MAXK) cnt = MAXK;

    // ---- direct register A-fragment gather ----
    union { bf16x8 v; uint4 u; } A0, A1, A2;
    A0.u = make_uint4(0,0,0,0); A1.u = A0.u; A2.u = A0.u;
    if (row < cnt) {
        int idx = lists[src];
        const float4* xp = reinterpret_cast<const float4*>(x + (size_t)idx*FDIM + rq*8);
        float4 u0 = xp[0], u1 = xp[1];
        const float4* xq = reinterpret_cast<const float4*>(x + (size_t)idx*FDIM + 32 + rq*8);
        float4 u2 = xq[0], u3 = xq[1];
        A0.u.x = pk2(u0.x, u0.y); A0.u.y = pk2(u0.z, u0.w);
        A0.u.z = pk2(u1.x, u1.y); A0.u.w = pk2(u1.z, u1.w);
        A1.u.x = pk2(u2.x, u2.y); A1.u.y = pk2(u2.z, u2.w);
        A1.u.z = pk2(u3.x, u3.y); A1.u.w = pk2(u3.z, u3.w);
        if (rq == 0) {                       // k=64..66 -> rel, rest 0
            float4 p = posq[idx];
            A2.u.x = pk2(p.x - q4.x, p.y - q4.y);
            A2.u.y = pk2(p.z - q4.z, 0.f);
        }
    }

    const bf16x8* W1f = reinterpret_cast<const bf16x8*>(W1bf);
    const bf16x8* W2f = reinterpret_cast<const bf16x8*>(W2bf);

    // ---- layer 1 ----
    #pragma unroll
    for (int cb = 0; cb < 8; ++cb) {
        f32x4 c = {0.f, 0.f, 0.f, 0.f};
        c = __builtin_amdgcn_mfma_f32_16x16x32_bf16(A0.v, W1f[(cb*3+0)*64 + lane], c, 0, 0, 0);
        c = __builtin_amdgcn_mfma_f32_16x16x32_bf16(A1.v, W1f[(cb*3+1)*64 + lane], c, 0, 0, 0);
        c = __builtin_amdgcn_mfma_f32_16x16x32_bf16(A2.v, W1f[(cb*3+2)*64 + lane], c, 0, 0, 0);
        int col = cb*16 + colq;
        float bias = b1[col];
        #pragma unroll
        for (int reg = 0; reg < 4; ++reg) {
            int r = rq*4 + reg;
            float h = fmaxf(c[reg] + bias, 0.f);
            // XOR-swizzled row-major [16][128] bf16 (ushort-index swizzle <<3)
            h_lds[w*2048 + r*128 + (col ^ ((r & 7) << 3))] = f2bf(h);
        }
    }
    // wave-local LDS RAW (wave w wrote & reads only its block): no barrier.

    // ---- layer 2 ----
    int r = colq, swz = (r & 7) << 3;
    bf16x8 g0 = *reinterpret_cast<const bf16x8*>(&h_lds[w*2048 + r*128 + ((  0 + rq*8) ^ swz)]);
    bf16x8 g1 = *reinterpret_cast<const bf16x8*>(&h_lds[w*2048 + r*128 + (( 32 + rq*8) ^ swz)]);
    bf16x8 g2 = *reinterpret_cast<const bf16x8*>(&h_lds[w*2048 + r*128 + (( 64 + rq*8) ^ swz)]);
    bf16x8 g3 = *reinterpret_cast<const bf16x8*>(&h_lds[w*2048 + r*128 + (( 96 + rq*8) ^ swz)]);
    #pragma unroll
    for (int cb = 0; cb < 8; ++cb) {
        f32x4 c = {0.f, 0.f, 0.f, 0.f};
        c = __builtin_amdgcn_mfma_f32_16x16x32_bf16(g0, W2f[(cb*4+0)*64 + lane], c, 0, 0, 0);
        c = __builtin_amdgcn_mfma_f32_16x16x32_bf16(g1, W2f[(cb*4+1)*64 + lane], c, 0, 0, 0);
        c = __builtin_amdgcn_mfma_f32_16x16x32_bf16(g2, W2f[(cb*4+2)*64 + lane], c, 0, 0, 0);
        c = __builtin_amdgcn_mfma_f32_16x16x32_bf16(g3, W2f[(cb*4+3)*64 + lane], c, 0, 0, 0);
        int col = cb*16 + colq;
        float bias = b2[col];
        float mx = -INFINITY;
        #pragma unroll
        for (int reg = 0; reg < 4; ++reg) {
            int rr = w*16 + rq*4 + reg;
            float val = c[reg] + bias;
            if (rr < cnt) mx = fmaxf(mx, val);
        }
        mx = fmaxf(mx, __shfl_xor(mx, 16, 64));   // reduce over rq
        mx = fmaxf(mx, __shfl_xor(mx, 32, 64));
        if (rq == 0) pmax_s[w][col] = mx;
    }
    __syncthreads();

    // ---- combine row-blocks, L2 normalize, store ----
    int c = tid & 127, g = tid >> 7;
    float v = fmaxf(fmaxf(pmax_s[0][c], pmax_s[1][c]),
                    fmaxf(pmax_s[2][c], pmax_s[3][c]));
    if (cnt == 0) v = 0.f;
    float s = (g == 0) ? v*v : 0.f;
    #pragma unroll
    for (int o = 32; o > 0; o >>= 1) s += __shfl_xor(s, o, 64);
    if (g == 0 && (tid & 63) == 0) rsum[tid >> 6] = s;
    __syncthreads();
    if (g == 0) {
        float nrm = fmaxf(sqrtf(rsum[0] + rsum[1]), 1e-12f);
        out[(size_t)m*HDIM + c] = v / nrm;
    }
}

extern "C" void kernel_launch(void* const* d_in, const int* in_sizes, int n_in,
                              void* d_out, int out_size, void* d_ws, size_t ws_size,
                              hipStream_t stream)
{
    const float* x       = (const float*)d_in[0];
    const float* pos     = (const float*)d_in[1];
    const float* W1      = (const float*)d_in[2];
    const float* b1      = (const float*)d_in[3];
    const float* W2      = (const float*)d_in[4];
    const float* b2      = (const float*)d_in[5];
    const int*   batch   = (const int*)d_in[6];
    const int*   key_idx = (const int*)d_in[7];

    int N = in_sizes[6];   // 100000
    int M = in_sizes[7];   // 2048

    unsigned short* W1bf = (unsigned short*)d_ws;                 // 24 KB
    unsigned short* W2bf = W1bf + 12288;                          // 32 KB
    float4* posq  = (float4*)(W2bf + 16384);                      // N*16 B
    int* bounds   = (int*)(posq + N);                             // 8 ints
    int* lists    = bounds + 8;                                   // M*16*64 ints
    int* lcnt     = lists + (size_t)M * NSPLIT * MAXK;            // M*16 ints

    int prep_blocks = (3584 + N + 5 + 255) / 256;
    prep_kernel<<<prep_blocks, 256, 0, stream>>>(W1, W2, pos, batch, N,
                                                 W1bf, W2bf, posq, bounds);
    scan_kernel<<<M*NSPLIT, 64, 0, stream>>>(posq, batch, key_idx, bounds,
                                             lists, lcnt);
    mlp_kernel<<<M, 256, 0, stream>>>(x, posq, W1bf, W2bf, b1, b2, key_idx,
                                      lists, lcnt, (float*)d_out, M);
}